// Round 7
// baseline (172.577 us; speedup 1.0000x reference)
//
#include <hip/hip_runtime.h>

#define NODE_IN 64
#define EDGE_IN 32
#define GLOBAL_IN 32
#define HID 128
#define EOUT 32

typedef float f32x4 __attribute__((ext_vector_type(4)));
typedef short s16x8 __attribute__((ext_vector_type(8)));
typedef unsigned short u16x8 __attribute__((ext_vector_type(8)));

// LDS map (single 37376 B block, no unions):
//   0     : Xsrc f32 [32][64]   8192 B   (row = 256 B = 16 chunks of 16 B)
//   8192  : Xdst f32 [32][64]   8192 B
//   16384 : Xea  f32 [32][32]   4096 B   (row = 128 B = 8 chunks)
//   20480 : u   bf16 [128][32]  8192 B   (row = 64 B; staged once per block)
//   28672 : H   bf16 [32][136]  8704 B   (row = 272 B)
#define XSRC 0
#define XDST 8192
#define XEA  16384
#define UOFF 20480
#define HOFF 28672
#define LDSZ 37376

__device__ __forceinline__ unsigned short f2bf(float f) {
  __bf16 h = (__bf16)f;
  return __builtin_bit_cast(unsigned short, h);
}

__device__ __forceinline__ s16x8 cvt8(f32x4 a, f32x4 b) {
  u16x8 v = { f2bf(a[0]), f2bf(a[1]), f2bf(a[2]), f2bf(a[3]),
              f2bf(b[0]), f2bf(b[1]), f2bf(b[2]), f2bf(b[3]) };
  return __builtin_bit_cast(s16x8, v);
}

// async global->LDS DMA, 16 B/lane; LDS dest = wave-uniform base + lane*16
__device__ __forceinline__ void glds16(const float* g, const char* l) {
  __builtin_amdgcn_global_load_lds(
      (const __attribute__((address_space(1))) unsigned int*)g,
      (__attribute__((address_space(3))) unsigned int*)l, 16, 0, 0);
}

// read f32 chunks {c, c+1} of a swizzled X row -> bf16 A-fragment
// (both-sides XOR-swizzle: slot = chunk ^ (row&7); involution, rule #21)
__device__ __forceinline__ s16x8 xfrag(const char* rowp, int c, int x) {
  const f32x4 a = *(const f32x4*)(rowp + ((c    ) ^ x) * 16);
  const f32x4 b = *(const f32x4*)(rowp + ((c + 1) ^ x) * 16);
  return cvt8(a, b);
}

// ============================================================================
// Tile = 32 edges, block = 4 waves, grid-stride. X staged as RAW F32 via
// global_load_lds (async DMA: no staging VGPRs -> regalloc can't sink the
// prefetch, the round-6 failure; no staging VALU), cvt to bf16 at consume.
// Global source is chunk-XOR-preswizzled so the 256B-stride row reads are
// bank-conflict-free. u[128][32] staged once per block as bf16 (kills the
// per-tile ebp->u HBM gather). One vmcnt(0) per tile at the loop seam; the
// next tile's 20 glds fly over epilogue + layer-2.
// L1: wave n-splits H cols [32w,32w+32) (paired-col B-frags -> packed dword
// H writes). L2: wave (mf=w>>1, nf=w&1) does rows 16mf..+16, cols 16nf..+16.
// ============================================================================
__global__ __launch_bounds__(256) void edge_mlp(
    const float* __restrict__ srcp, const float* __restrict__ dstp,
    const float* __restrict__ eap, const float* __restrict__ up,
    const int* __restrict__ ebp, const float* __restrict__ W1,
    const float* __restrict__ b1, const float* __restrict__ W2,
    const float* __restrict__ b2, float* __restrict__ outp,
    int E, int ntiles)
{
  __shared__ __align__(16) char SM[LDSZ];

  const int t = threadIdx.x;
  const int wid = t >> 6;
  const int lane = t & 63;
  const int g = lane >> 4;
  const int r16 = lane & 15;
  const int Em1 = E - 1;

  // ---- weight fragments in registers ----
  // L1 B-frag, paired cols: lane r16 of frag nt holds W1 col 32*wid+2*r16+nt
  s16x8 w1f[6][2];
#pragma unroll
  for (int kk = 0; kk < 6; ++kk) {
#pragma unroll
    for (int nt = 0; nt < 2; ++nt) {
      s16x8 v;
#pragma unroll
      for (int j = 0; j < 8; ++j)
        v[j] = (short)f2bf(W1[(32*kk + 8*g + j)*HID + 32*wid + 2*r16 + nt]);
      w1f[kk][nt] = v;
    }
  }
  const int mf = wid >> 1, nf = wid & 1;
  s16x8 w2f[4];
#pragma unroll
  for (int kk = 0; kk < 4; ++kk) {
    s16x8 v;
#pragma unroll
    for (int j = 0; j < 8; ++j)
      v[j] = (short)f2bf(W2[(32*kk + 8*g + j)*EOUT + 16*nf + r16]);
    w2f[kk] = v;
  }
  const float b1v0 = b1[32*wid + 2*r16];
  const float b1v1 = b1[32*wid + 2*r16 + 1];
  const float b2v  = b2[16*nf + r16];

  // ---- stage u (once per block): f32 -> bf16 [128][32] ----
  {
    const int row = t >> 1, half = t & 1;
    const float* pu = up + row * GLOBAL_IN + half * 16;
    const f32x4 u0 = *(const f32x4*)pu,      u1 = *(const f32x4*)(pu + 4);
    const f32x4 u2 = *(const f32x4*)(pu + 8), u3 = *(const f32x4*)(pu + 12);
    *(u16x8*)(SM + UOFF + row*64 + half*32)      = __builtin_bit_cast(u16x8, cvt8(u0, u1));
    *(u16x8*)(SM + UOFF + row*64 + half*32 + 16) = __builtin_bit_cast(u16x8, cvt8(u2, u3));
  }

  // ---- glds staging: 20 instrs/tile, 5 per wave; src pre-swizzled ----
  auto stage = [&](int tb) {
#pragma unroll
    for (int k = 0; k < 5; ++k) {
      const int i = 5*wid + k;
      if (i < 8) {                       // src, instr covers rows 4i..4i+3
        const int rl = lane >> 4, c = lane & 15, r = 4*i + rl;
        const int gr = min(tb + r, Em1);
        glds16(srcp + (size_t)gr*NODE_IN + ((c ^ (r & 7)) * 4),
               SM + XSRC + i*1024);
      } else if (i < 16) {               // dst
        const int q = i - 8;
        const int rl = lane >> 4, c = lane & 15, r = 4*q + rl;
        const int gr = min(tb + r, Em1);
        glds16(dstp + (size_t)gr*NODE_IN + ((c ^ (r & 7)) * 4),
               SM + XDST + q*1024);
      } else {                           // ea, instr covers rows 8q..8q+7
        const int q = i - 16;
        const int rl = lane >> 3, c = lane & 7, r = 8*q + rl;
        const int gr = min(tb + r, Em1);
        glds16(eap + (size_t)gr*EDGE_IN + ((c ^ (r & 7)) * 4),
               SM + XEA + q*1024);
      }
    }
  };

  int tile = blockIdx.x;
  const int TS = gridDim.x;

  // ---- prologue ----
  stage(tile * 32);
  int bbv0 = ebp[min(tile*32 + r16,      Em1)];
  int bbv1 = ebp[min(tile*32 + 16 + r16, Em1)];
  asm volatile("s_waitcnt vmcnt(0) lgkmcnt(0)" ::: "memory");
  __builtin_amdgcn_s_barrier();          // X(t0) + u staged

  for (; tile < ntiles; tile += TS) {
    const int tb = tile * 32;

    // ---- layer 1: 2 m-frags x 2 n-frags, K=192 (160 from X-f32, 32 from u) ----
    f32x4 acc[2][2];
    {
      const f32x4 z = {0.f, 0.f, 0.f, 0.f};
      acc[0][0] = z; acc[0][1] = z; acc[1][0] = z; acc[1][1] = z;
    }
#pragma unroll
    for (int mi = 0; mi < 2; ++mi) {
      const int r = 16*mi + r16;
      const int x = r & 7;
      const char* Sr = SM + XSRC + r*256;
      const char* Dr = SM + XDST + r*256;
      const char* Er = SM + XEA  + r*128;
      const s16x8 f0 = xfrag(Sr, 2*g,     x);
      const s16x8 f1 = xfrag(Sr, 8 + 2*g, x);
      const s16x8 f2 = xfrag(Dr, 2*g,     x);
      const s16x8 f3 = xfrag(Dr, 8 + 2*g, x);
      const s16x8 f4 = xfrag(Er, 2*g,     x);
      const int bb = mi ? bbv1 : bbv0;
      const s16x8 f5 = *(const s16x8*)(SM + UOFF + bb*64 + g*16);
      acc[mi][0] = __builtin_amdgcn_mfma_f32_16x16x32_bf16(f0, w1f[0][0], acc[mi][0], 0, 0, 0);
      acc[mi][1] = __builtin_amdgcn_mfma_f32_16x16x32_bf16(f0, w1f[0][1], acc[mi][1], 0, 0, 0);
      acc[mi][0] = __builtin_amdgcn_mfma_f32_16x16x32_bf16(f1, w1f[1][0], acc[mi][0], 0, 0, 0);
      acc[mi][1] = __builtin_amdgcn_mfma_f32_16x16x32_bf16(f1, w1f[1][1], acc[mi][1], 0, 0, 0);
      acc[mi][0] = __builtin_amdgcn_mfma_f32_16x16x32_bf16(f2, w1f[2][0], acc[mi][0], 0, 0, 0);
      acc[mi][1] = __builtin_amdgcn_mfma_f32_16x16x32_bf16(f2, w1f[2][1], acc[mi][1], 0, 0, 0);
      acc[mi][0] = __builtin_amdgcn_mfma_f32_16x16x32_bf16(f3, w1f[3][0], acc[mi][0], 0, 0, 0);
      acc[mi][1] = __builtin_amdgcn_mfma_f32_16x16x32_bf16(f3, w1f[3][1], acc[mi][1], 0, 0, 0);
      acc[mi][0] = __builtin_amdgcn_mfma_f32_16x16x32_bf16(f4, w1f[4][0], acc[mi][0], 0, 0, 0);
      acc[mi][1] = __builtin_amdgcn_mfma_f32_16x16x32_bf16(f4, w1f[4][1], acc[mi][1], 0, 0, 0);
      acc[mi][0] = __builtin_amdgcn_mfma_f32_16x16x32_bf16(f5, w1f[5][0], acc[mi][0], 0, 0, 0);
      acc[mi][1] = __builtin_amdgcn_mfma_f32_16x16x32_bf16(f5, w1f[5][1], acc[mi][1], 0, 0, 0);
    }
    asm volatile("s_waitcnt lgkmcnt(0)" ::: "memory");
    __builtin_amdgcn_s_barrier();        // all X reads done -> safe to overwrite

    // ---- issue next tile's DMA (flies over epilogue + L2) ----
    stage((tile + TS) * 32);
    const int nb = min((tile + TS) * 32, Em1 - 16 > 0 ? Em1 : Em1); // base for bbv prefetch
    bbv0 = ebp[min((tile + TS)*32 + r16,      Em1)];
    bbv1 = ebp[min((tile + TS)*32 + 16 + r16, Em1)];
    (void)nb;

    // ---- epilogue: +b1, relu, packed dword -> H ----
#pragma unroll
    for (int mi = 0; mi < 2; ++mi) {
#pragma unroll
      for (int j = 0; j < 4; ++j) {
        const float h0 = fmaxf(acc[mi][0][j] + b1v0, 0.f);
        const float h1 = fmaxf(acc[mi][1][j] + b1v1, 0.f);
        const unsigned int pk = (unsigned int)f2bf(h0) |
                                ((unsigned int)f2bf(h1) << 16);
        *(unsigned int*)(SM + HOFF + (16*mi + 4*g + j)*272 + (32*wid + 2*r16)*2) = pk;
      }
    }
    asm volatile("s_waitcnt lgkmcnt(0)" ::: "memory");
    __builtin_amdgcn_s_barrier();        // H ready (vmcnt NOT drained)

    // ---- layer 2: rows 16mf..+16, cols 16nf..+16, K=128 ----
    f32x4 acc2;
    { const f32x4 z = {0.f, 0.f, 0.f, 0.f}; acc2 = z; }
#pragma unroll
    for (int kk = 0; kk < 4; ++kk) {
      const s16x8 ah = *(const s16x8*)(SM + HOFF + (16*mf + r16)*272 + (32*kk + 8*g)*2);
      acc2 = __builtin_amdgcn_mfma_f32_16x16x32_bf16(ah, w2f[kk], acc2, 0, 0, 0);
    }
#pragma unroll
    for (int j = 0; j < 4; ++j) {
      const int m = tb + 16*mf + 4*g + j;
      if (m < E) outp[(size_t)m*EOUT + 16*nf + r16] = acc2[j] + b2v;
    }

    // ---- seam: X(t+1) DMA landed + H reads done ----
    asm volatile("s_waitcnt vmcnt(0) lgkmcnt(0)" ::: "memory");
    __builtin_amdgcn_s_barrier();
  }
}

extern "C" void kernel_launch(void* const* d_in, const int* in_sizes, int n_in,
                              void* d_out, int out_size, void* d_ws, size_t ws_size,
                              hipStream_t stream) {
  const float* srcp = (const float*)d_in[0];
  const float* dstp = (const float*)d_in[1];
  const float* eap  = (const float*)d_in[2];
  const float* up   = (const float*)d_in[3];
  const int*   ebp  = (const int*)d_in[4];
  const float* W1   = (const float*)d_in[5];
  const float* b1   = (const float*)d_in[6];
  const float* W2   = (const float*)d_in[7];
  const float* b2   = (const float*)d_in[8];
  float* outp = (float*)d_out;

  const int E = in_sizes[0] / NODE_IN;
  const int ntiles = (E + 31) / 32;
  const int grid = ntiles < 2048 ? ntiles : 2048;

  edge_mlp<<<grid, 256, 0, stream>>>(srcp, dstp, eap, up, ebp, W1, b1, W2, b2,
                                     outp, E, ntiles);
}

// Round 8
// 159.001 us; speedup vs baseline: 1.0854x; 1.0854x over previous
//
#include <hip/hip_runtime.h>

#define NODE_IN 64
#define EDGE_IN 32
#define GLOBAL_IN 32
#define HID 128
#define EOUT 32

typedef float f32x4 __attribute__((ext_vector_type(4)));
typedef float f32x2 __attribute__((ext_vector_type(2)));
typedef short s16x8 __attribute__((ext_vector_type(8)));
typedef unsigned short u16x8 __attribute__((ext_vector_type(8)));

// LDS: X bf16 [64][192] (384 B rows, 24 x 16B chunks: src 0-7 | dst 8-15 |
// ea 16-19(+u 20-23), chunk-XOR swizzled) + H bf16 [64][128] (256 B rows,
// chunk-XOR swizzled). 384 % 128 == 0 -> no row bank-skew, so the XOR gives
// exactly 2-way (free) access on all hot reads.
#define XROW 384
#define HOFF 24576
#define LDSZ 40960

// volatile asm loads: regalloc can NOT sink or delete these (rounds 5/6
// evidence: non-volatile prefetch was sunk to use, VGPR 100-128 tell).
#define GLOADX4(dst, ptr) asm volatile("global_load_dwordx4 %0, %1, off" : "=v"(dst) : "v"(ptr))
#define GLOADD(dst, ptr)  asm volatile("global_load_dword %0, %1, off"   : "=v"(dst) : "v"(ptr))

__device__ __forceinline__ unsigned short f2bf(float f) {
  __bf16 h = (__bf16)f;
  return __builtin_bit_cast(unsigned short, h);
}

__device__ __forceinline__ s16x8 cvt8(f32x4 a, f32x4 b) {
  u16x8 v = { f2bf(a[0]), f2bf(a[1]), f2bf(a[2]), f2bf(a[3]),
              f2bf(b[0]), f2bf(b[1]), f2bf(b[2]), f2bf(b[3]) };
  return __builtin_bit_cast(s16x8, v);
}

__device__ __forceinline__ void bar_lds() {     // lgkm-only barrier (T4):
  asm volatile("s_waitcnt lgkmcnt(0)" ::: "memory");
  __builtin_amdgcn_s_barrier();
  asm volatile("" ::: "memory");
}

// Block = 4 waves, tile = 64 edges, grid-stride; 2 lgkm barriers/tile.
// Pipeline: P(regs) holds tile t+1 in flight during tile t; one vmcnt(0)
// per tile placed where outstanding loads are a full iteration old (~free).
// ebp prefetched 2 tiles deep (covers the ebp->u dependent gather).
__global__ __launch_bounds__(256) void edge_mlp(
    const float* __restrict__ srcp, const float* __restrict__ dstp,
    const float* __restrict__ eap, const float* __restrict__ up,
    const int* __restrict__ ebp, const float* __restrict__ W1,
    const float* __restrict__ b1, const float* __restrict__ W2,
    const float* __restrict__ b2, float* __restrict__ outp,
    int E, int ntiles)
{
  __shared__ __align__(16) char SM[LDSZ];

  const int t = threadIdx.x;
  const int wid = t >> 6;
  const int lane = t & 63;
  const int g = lane >> 4;
  const int r16 = lane & 15;
  const int rA = t >> 3, cA8 = (t & 7) * 8;   // src/dst staging rows rA, rA+32
  const int rC = t >> 2, cC8 = (t & 3) * 8;   // ea/u staging row
  const int Em1 = E - 1;

  // ---- weight fragments (registers, once per block) ----
  // w1f paired cols: lane r16 of frag nt -> H col 32*wid + 2*r16 + nt
  s16x8 w1f[6][2];
#pragma unroll
  for (int kk = 0; kk < 6; ++kk) {
#pragma unroll
    for (int nt = 0; nt < 2; ++nt) {
      s16x8 v;
#pragma unroll
      for (int j = 0; j < 8; ++j)
        v[j] = (short)f2bf(W1[(32*kk + 8*g + j)*HID + 32*wid + 2*r16 + nt]);
      w1f[kk][nt] = v;
    }
  }
  s16x8 w2f[4][2];
#pragma unroll
  for (int kk = 0; kk < 4; ++kk) {
#pragma unroll
    for (int nt = 0; nt < 2; ++nt) {
      s16x8 v;
#pragma unroll
      for (int j = 0; j < 8; ++j)
        v[j] = (short)f2bf(W2[(32*kk + 8*g + j)*EOUT + 2*r16 + nt]);
      w2f[kk][nt] = v;
    }
  }
  const float b1v0 = b1[32*wid + 2*r16];
  const float b1v1 = b1[32*wid + 2*r16 + 1];
  const float b2v0 = b2[2*r16];
  const float b2v1 = b2[2*r16 + 1];

  // ---- pinned prefetch registers (one 64-edge tile slice / thread) ----
  f32x4 P0, P1, P2, P3, P4, P5, P6, P7, P8, P9, P10, P11;

  auto issue_gloads = [&](int mb, int eb) {
    const int r0 = min(mb + rA, Em1);
    const int r1 = min(mb + 32 + rA, Em1);
    const int r2 = min(mb + rC, Em1);
    const float* s0 = srcp + (size_t)r0 * NODE_IN + cA8;
    const float* s1 = srcp + (size_t)r1 * NODE_IN + cA8;
    const float* d0 = dstp + (size_t)r0 * NODE_IN + cA8;
    const float* d1 = dstp + (size_t)r1 * NODE_IN + cA8;
    const float* e0 = eap  + (size_t)r2 * EDGE_IN + cC8;
    const float* u0 = up   + (size_t)eb * GLOBAL_IN + cC8;
    GLOADX4(P0, s0);  GLOADX4(P1, s0 + 4);
    GLOADX4(P2, s1);  GLOADX4(P3, s1 + 4);
    GLOADX4(P4, d0);  GLOADX4(P5, d0 + 4);
    GLOADX4(P6, d1);  GLOADX4(P7, d1 + 4);
    GLOADX4(P8, e0);  GLOADX4(P9, e0 + 4);
    GLOADX4(P10, u0); GLOADX4(P11, u0 + 4);
  };

  // write-side chunk swizzle (involution c ^= row&7 within each 8-group)
  const int sxw = (t & 7) ^ (rA & 7);          // src/dst chunk (rows rA, rA+32 same &7)
  const int sew = ((t & 3)     ) ^ (rC & 7);   // ea chunk in 0..7
  const int suw = (4 + (t & 3) ) ^ (rC & 7);   // u  chunk in 0..7
  auto write_x = [&]() {
    *(s16x8*)(SM + rA*XROW        + sxw*16)        = cvt8(P0, P1);
    *(s16x8*)(SM + (rA+32)*XROW   + sxw*16)        = cvt8(P2, P3);
    *(s16x8*)(SM + rA*XROW        + (8+sxw)*16)    = cvt8(P4, P5);
    *(s16x8*)(SM + (rA+32)*XROW   + (8+sxw)*16)    = cvt8(P6, P7);
    *(s16x8*)(SM + rC*XROW        + (16+sew)*16)   = cvt8(P8, P9);
    *(s16x8*)(SM + rC*XROW        + (16+suw)*16)   = cvt8(P10, P11);
  };

  int tile = blockIdx.x;
  const int TS = gridDim.x;
  int ebv;

  // ---- prologue ----
  {
    const int eb0 = ebp[min(tile*64 + rC, Em1)];
    const int eb1 = ebp[min((tile + TS)*64 + rC, Em1)];
    issue_gloads(tile * 64, eb0);
    asm volatile("s_waitcnt vmcnt(0)" ::: "memory");
    __builtin_amdgcn_sched_barrier(0);
    write_x();                                  // SMX = tile0
    issue_gloads((tile + TS) * 64, eb1);        // tile1 in flight
    GLOADD(ebv, (ebp + min((tile + 2*TS)*64 + rC, Em1)));
  }
  bar_lds();                                    // X(tile0) staged

  for (; tile < ntiles; tile += TS) {
    const int mbase = tile * 64;

    // ---- layer 1: 4 m-tiles x 2 n-frags, K=192, swizzled SMX reads ----
    f32x4 acc[4][2];
    {
      const f32x4 z = {0.f, 0.f, 0.f, 0.f};
#pragma unroll
      for (int mi = 0; mi < 4; ++mi) { acc[mi][0] = z; acc[mi][1] = z; }
    }
#pragma unroll
    for (int mi = 0; mi < 4; ++mi) {
      const int r = 16*mi + r16;
      const char* Rp = SM + r * XROW;
      const int s = r16 & 7;
      const s16x8 f0 = *(const s16x8*)(Rp + ((g     ^ s)      )*16);
      const s16x8 f1 = *(const s16x8*)(Rp + (((4+g) ^ s)      )*16);
      const s16x8 f2 = *(const s16x8*)(Rp + ((g     ^ s) +  8 )*16);
      const s16x8 f3 = *(const s16x8*)(Rp + (((4+g) ^ s) +  8 )*16);
      const s16x8 f4 = *(const s16x8*)(Rp + ((g     ^ s) + 16 )*16);
      const s16x8 f5 = *(const s16x8*)(Rp + (((4+g) ^ s) + 16 )*16);
      acc[mi][0] = __builtin_amdgcn_mfma_f32_16x16x32_bf16(f0, w1f[0][0], acc[mi][0], 0, 0, 0);
      acc[mi][1] = __builtin_amdgcn_mfma_f32_16x16x32_bf16(f0, w1f[0][1], acc[mi][1], 0, 0, 0);
      acc[mi][0] = __builtin_amdgcn_mfma_f32_16x16x32_bf16(f1, w1f[1][0], acc[mi][0], 0, 0, 0);
      acc[mi][1] = __builtin_amdgcn_mfma_f32_16x16x32_bf16(f1, w1f[1][1], acc[mi][1], 0, 0, 0);
      acc[mi][0] = __builtin_amdgcn_mfma_f32_16x16x32_bf16(f2, w1f[2][0], acc[mi][0], 0, 0, 0);
      acc[mi][1] = __builtin_amdgcn_mfma_f32_16x16x32_bf16(f2, w1f[2][1], acc[mi][1], 0, 0, 0);
      acc[mi][0] = __builtin_amdgcn_mfma_f32_16x16x32_bf16(f3, w1f[3][0], acc[mi][0], 0, 0, 0);
      acc[mi][1] = __builtin_amdgcn_mfma_f32_16x16x32_bf16(f3, w1f[3][1], acc[mi][1], 0, 0, 0);
      acc[mi][0] = __builtin_amdgcn_mfma_f32_16x16x32_bf16(f4, w1f[4][0], acc[mi][0], 0, 0, 0);
      acc[mi][1] = __builtin_amdgcn_mfma_f32_16x16x32_bf16(f4, w1f[4][1], acc[mi][1], 0, 0, 0);
      acc[mi][0] = __builtin_amdgcn_mfma_f32_16x16x32_bf16(f5, w1f[5][0], acc[mi][0], 0, 0, 0);
      acc[mi][1] = __builtin_amdgcn_mfma_f32_16x16x32_bf16(f5, w1f[5][1], acc[mi][1], 0, 0, 0);
    }

    // ---- epilogue: +b1, relu, packed dword -> swizzled H ----
#pragma unroll
    for (int mi = 0; mi < 4; ++mi) {
#pragma unroll
      for (int j = 0; j < 4; ++j) {
        const float h0 = fmaxf(acc[mi][0][j] + b1v0, 0.f);
        const float h1 = fmaxf(acc[mi][1][j] + b1v1, 0.f);
        const unsigned int pk = (unsigned int)f2bf(h0) |
                                ((unsigned int)f2bf(h1) << 16);
        const int row = 16*mi + 4*g + j;
        const int ch = (4*wid + (r16 >> 2)) ^ ((4*g + j) & 7);
        *(unsigned int*)(SM + HOFF + row*256 + ch*16 + (r16 & 3)*4) = pk;
      }
    }
    bar_lds();          // B1: H ready; all SMX(t) reads done

    // ---- stage tile+TS (P arrived ~1 iteration ago -> near-free wait) ----
    asm volatile("s_waitcnt vmcnt(0)" ::: "memory");
    __builtin_amdgcn_sched_barrier(0);
    write_x();
    issue_gloads((tile + 2*TS) * 64, ebv);      // flies over L2 + next L1
    GLOADD(ebv, (ebp + min((tile + 3*TS)*64 + rC, Em1)));

    // ---- layer 2: 16 rows/wave, K=128, swizzled H reads ----
    f32x4 acc2[2];
    {
      const f32x4 z = {0.f, 0.f, 0.f, 0.f};
      acc2[0] = z; acc2[1] = z;
    }
#pragma unroll
    for (int kk = 0; kk < 4; ++kk) {
      const int ch = (4*kk + g) ^ (r16 & 7);
      const s16x8 ah = *(const s16x8*)(SM + HOFF + (16*wid + r16)*256 + ch*16);
      acc2[0] = __builtin_amdgcn_mfma_f32_16x16x32_bf16(ah, w2f[kk][0], acc2[0], 0, 0, 0);
      acc2[1] = __builtin_amdgcn_mfma_f32_16x16x32_bf16(ah, w2f[kk][1], acc2[1], 0, 0, 0);
    }
#pragma unroll
    for (int j = 0; j < 4; ++j) {
      const int m = mbase + 16*wid + 4*g + j;
      if (m < E) {
        f32x2 o = { acc2[0][j] + b2v0, acc2[1][j] + b2v1 };
        *(f32x2*)(outp + (size_t)m*EOUT + 2*r16) = o;
      }
    }
    bar_lds();          // B2: SMX(t+1) staged; H reads done (WAR for next epi)
  }
}

extern "C" void kernel_launch(void* const* d_in, const int* in_sizes, int n_in,
                              void* d_out, int out_size, void* d_ws, size_t ws_size,
                              hipStream_t stream) {
  const float* srcp = (const float*)d_in[0];
  const float* dstp = (const float*)d_in[1];
  const float* eap  = (const float*)d_in[2];
  const float* up   = (const float*)d_in[3];
  const int*   ebp  = (const int*)d_in[4];
  const float* W1   = (const float*)d_in[5];
  const float* b1   = (const float*)d_in[6];
  const float* W2   = (const float*)d_in[7];
  const float* b2   = (const float*)d_in[8];
  float* outp = (float*)d_out;

  const int E = in_sizes[0] / NODE_IN;
  const int ntiles = (E + 63) / 64;
  const int grid = ntiles < 2048 ? ntiles : 2048;

  edge_mlp<<<grid, 256, 0, stream>>>(srcp, dstp, eap, up, ebp, W1, b1, W2, b2,
                                     outp, E, ntiles);
}